// Round 6
// baseline (540.975 us; speedup 1.0000x reference)
//
#include <hip/hip_runtime.h>
#include <math.h>
#include <stdint.h>

#define D_MODEL 2048
#define NHEAD   16
#define DK      128
#define SEQ     2048
#define BATCH   2
#define MROWS   (BATCH * SEQ)   // 4096

typedef __bf16 bf16;
typedef __bf16 bf16x8 __attribute__((ext_vector_type(8)));
typedef __bf16 bf16x4 __attribute__((ext_vector_type(4)));
typedef float  f32x4  __attribute__((ext_vector_type(4)));

__device__ __forceinline__ bf16 f2bf(float f) {
    unsigned u = __builtin_bit_cast(unsigned, f);
    u += 0x7fffu + ((u >> 16) & 1u);   // round-to-nearest-even
    unsigned short h = (unsigned short)(u >> 16);
    return __builtin_bit_cast(bf16, h);
}

#define GLDS16(gp, lp)                                                        \
    __builtin_amdgcn_global_load_lds(                                         \
        (__attribute__((address_space(1))) void*)(uintptr_t)(gp),             \
        (__attribute__((address_space(3))) void*)(lp), 16, 0, 0)

#define QSCALE 0.08838834764831845f  // 1/sqrt(128)

// ---------------- fused fp32 -> bf16 convert (all 5 tensors, 1 launch) -----
// X (NX4 float4s) -> dX;  W0..W3 (NW4 float4s each) -> dW + s*NW (contiguous)
__global__ void cvt_all(const float* __restrict__ X, const float* __restrict__ W0,
                        const float* __restrict__ W1, const float* __restrict__ W2,
                        const float* __restrict__ W3, bf16* __restrict__ dX,
                        bf16* __restrict__ dW) {
    const int NX4 = (MROWS * D_MODEL) / 4;            // 2,097,152
    const int NW4 = (D_MODEL * D_MODEL) / 4;          // 1,048,576 = 2^20
    const int TOT = NX4 + 4 * NW4;
    const int stride = gridDim.x * blockDim.x;
    for (int i = blockIdx.x * blockDim.x + threadIdx.x; i < TOT; i += stride) {
        const float* sp;
        bf16* dp;
        if (i < NX4) {
            sp = X + (size_t)i * 4;
            dp = dX + (size_t)i * 4;
        } else {
            int j = i - NX4;
            int s = j >> 20;
            int off = j & (NW4 - 1);
            const float* w = (s == 0) ? W0 : (s == 1) ? W1 : (s == 2) ? W2 : W3;
            sp = w + (size_t)off * 4;
            dp = dW + ((size_t)s << 22) + (size_t)off * 4;
        }
        float4 v = *(const float4*)sp;
        bf16x4 o;
        o[0] = f2bf(v.x); o[1] = f2bf(v.y); o[2] = f2bf(v.z); o[3] = f2bf(v.w);
        *(bf16x4*)dp = o;
    }
}

// ---------------- fused QKV GEMM ----------------
// C = X[4096,2048] @ Wqkv[6144,2048]^T.  Per-block epilogue:
//   cols [0,2048)    -> Qb  (bf16, scaled by QSCALE)
//   cols [2048,4096) -> Kbf (bf16)
//   cols [4096,6144) -> Vt  (bf16, transposed per (b,h): Vt[(b*16+h)*128+d][s])
__global__ __launch_bounds__(256)
void gemm_qkv(const bf16* __restrict__ A, const bf16* __restrict__ B,
              bf16* __restrict__ Qb, bf16* __restrict__ Kbf,
              bf16* __restrict__ Vt) {
    __shared__ alignas(16) bf16 sA[128 * 32];
    __shared__ alignas(16) bf16 sB[128 * 32];
    const int K = D_MODEL;

    const int tid  = threadIdx.x;
    const int lane = tid & 63;
    const int wid  = tid >> 6;
    const int wm   = wid >> 1, wn = wid & 1;
    const int brow = blockIdx.y * 128, bcol = blockIdx.x * 128;
    const int r16  = lane & 15, g = lane >> 4;

    f32x4 acc[4][4] = {};

    const int c0 = tid, c1 = 256 + tid;
    const int rowS0 = c0 >> 2, colS0 = (c0 & 3) * 8;
    const int rowS1 = c1 >> 2, colS1 = (c1 & 3) * 8;

    for (int kt = 0; kt < K; kt += 32) {
        GLDS16(A + (size_t)(brow + rowS0) * K + kt + colS0, &sA[c0 * 8]);
        GLDS16(A + (size_t)(brow + rowS1) * K + kt + colS1, &sA[c1 * 8]);
        GLDS16(B + (size_t)(bcol + rowS0) * K + kt + colS0, &sB[c0 * 8]);
        GLDS16(B + (size_t)(bcol + rowS1) * K + kt + colS1, &sB[c1 * 8]);
        __syncthreads();

        bf16x8 af[4], bfr[4];
#pragma unroll
        for (int m = 0; m < 4; ++m)
            af[m] = *(const bf16x8*)&sA[(wm * 64 + m * 16 + r16) * 32 + g * 8];
#pragma unroll
        for (int n = 0; n < 4; ++n)
            bfr[n] = *(const bf16x8*)&sB[(wn * 64 + n * 16 + r16) * 32 + g * 8];
#pragma unroll
        for (int m = 0; m < 4; ++m)
#pragma unroll
            for (int n = 0; n < 4; ++n)
                acc[m][n] = __builtin_amdgcn_mfma_f32_16x16x32_bf16(
                    af[m], bfr[n], acc[m][n], 0, 0, 0);
        __syncthreads();
    }

    const int which = bcol >> 11;  // 0=Q, 1=K, 2=V (tiles never straddle)
#pragma unroll
    for (int m = 0; m < 4; ++m) {
#pragma unroll
        for (int n = 0; n < 4; ++n) {
            const int col  = bcol + wn * 64 + n * 16 + r16;
            const int row0 = brow + wm * 64 + m * 16 + g * 4;
            if (which == 0) {
#pragma unroll
                for (int r = 0; r < 4; ++r)
                    Qb[(size_t)(row0 + r) * D_MODEL + col] =
                        f2bf(acc[m][n][r] * QSCALE);
            } else if (which == 1) {
#pragma unroll
                for (int r = 0; r < 4; ++r)
                    Kbf[(size_t)(row0 + r) * D_MODEL + (col - 2048)] =
                        f2bf(acc[m][n][r]);
            } else {
                const int b = row0 >> 11, s = row0 & 2047;
                bf16x4 v;
#pragma unroll
                for (int r = 0; r < 4; ++r) v[r] = f2bf(acc[m][n][r]);
                *(bf16x4*)&Vt[(size_t)(b * 2048 + (col - 4096)) * 2048 + s] = v;
            }
        }
    }
}

// ---------------- O-projection GEMM (bf16 in, fp32 out) ----------------
__global__ __launch_bounds__(256)
void gemm_o(const bf16* __restrict__ A, const bf16* __restrict__ B,
            float* __restrict__ C) {
    __shared__ alignas(16) bf16 sA[128 * 32];
    __shared__ alignas(16) bf16 sB[128 * 32];
    const int K = D_MODEL, N = D_MODEL;

    const int tid  = threadIdx.x;
    const int lane = tid & 63;
    const int wid  = tid >> 6;
    const int wm   = wid >> 1, wn = wid & 1;
    const int brow = blockIdx.y * 128, bcol = blockIdx.x * 128;
    const int r16  = lane & 15, g = lane >> 4;

    f32x4 acc[4][4] = {};

    const int c0 = tid, c1 = 256 + tid;
    const int rowS0 = c0 >> 2, colS0 = (c0 & 3) * 8;
    const int rowS1 = c1 >> 2, colS1 = (c1 & 3) * 8;

    for (int kt = 0; kt < K; kt += 32) {
        GLDS16(A + (size_t)(brow + rowS0) * K + kt + colS0, &sA[c0 * 8]);
        GLDS16(A + (size_t)(brow + rowS1) * K + kt + colS1, &sA[c1 * 8]);
        GLDS16(B + (size_t)(bcol + rowS0) * K + kt + colS0, &sB[c0 * 8]);
        GLDS16(B + (size_t)(bcol + rowS1) * K + kt + colS1, &sB[c1 * 8]);
        __syncthreads();

        bf16x8 af[4], bfr[4];
#pragma unroll
        for (int m = 0; m < 4; ++m)
            af[m] = *(const bf16x8*)&sA[(wm * 64 + m * 16 + r16) * 32 + g * 8];
#pragma unroll
        for (int n = 0; n < 4; ++n)
            bfr[n] = *(const bf16x8*)&sB[(wn * 64 + n * 16 + r16) * 32 + g * 8];
#pragma unroll
        for (int m = 0; m < 4; ++m)
#pragma unroll
            for (int n = 0; n < 4; ++n)
                acc[m][n] = __builtin_amdgcn_mfma_f32_16x16x32_bf16(
                    af[m], bfr[n], acc[m][n], 0, 0, 0);
        __syncthreads();
    }

#pragma unroll
    for (int m = 0; m < 4; ++m)
#pragma unroll
        for (int n = 0; n < 4; ++n) {
            const int col  = bcol + wn * 64 + n * 16 + r16;
            const int row0 = brow + wm * 64 + m * 16 + g * 4;
#pragma unroll
            for (int r = 0; r < 4; ++r)
                C[(size_t)(row0 + r) * N + col] = acc[m][n][r];
        }
}

// ---------------- causal flash attention ----------------
// 512 blocks; lin = bx + 16*by decodes to (qt, bh) such that
//   - all 16 q-tiles of a head land on one XCD (lin%8 fixed per bh group)
//     -> that XCD's L2 holds just 4 heads' K/V (~4 MB)
//   - dispatch pairs (qt, qt+8) per CU -> causal work balanced.
// 4 waves x 32 q-rows, KVBLK=64, direct global K/V reads (L2-served),
// no barriers: waves fully independent for latency hiding.
__global__ __launch_bounds__(256)
void attn_fwd(const bf16* __restrict__ Q, const bf16* __restrict__ Kb,
              const bf16* __restrict__ Vt, bf16* __restrict__ AO) {
    __shared__ alignas(16) bf16 P_lds[4][32][72];  // 144B row stride

    const int tid  = threadIdx.x;
    const int lane = tid & 63;
    const int wid  = tid >> 6;
    const int r16  = lane & 15, g = lane >> 4;
    const int lin  = (int)blockIdx.x + 16 * (int)blockIdx.y;
    const int bh   = (lin & 7) * 4 + ((lin >> 3) & 3);
    const int qt   = lin >> 5;
    const int b    = bh >> 4;
    const int qbase = qt * 128 + wid * 32;
    const size_t rowbase = (size_t)b * SEQ;
    const int hcol = (bh & 15) * DK;

    // Q fragments (pre-scaled by QSCALE in gemm_qkv epilogue)
    bf16x8 aq[2][4];
#pragma unroll
    for (int m = 0; m < 2; ++m) {
        const bf16* qp =
            Q + (rowbase + qbase + m * 16 + r16) * D_MODEL + hcol + g * 8;
#pragma unroll
        for (int c = 0; c < 4; ++c) aq[m][c] = *(const bf16x8*)(qp + c * 32);
    }

    f32x4 o[2][8] = {};
    float m_run[2][4], l_run[2][4];
#pragma unroll
    for (int m = 0; m < 2; ++m)
#pragma unroll
        for (int r = 0; r < 4; ++r) {
            m_run[m][r] = -3.0e38f;
            l_run[m][r] = 0.f;
        }

    const int ntile = (qbase >> 6) + 1;  // kv tiles of 64
    for (int t = 0; t < ntile; ++t) {
        const int kv0 = t * 64;

        // ---- QK^T (K direct from global; rows L2-resident per-XCD) ----
        f32x4 s[2][4] = {};
#pragma unroll
        for (int c = 0; c < 4; ++c) {
            bf16x8 kf[4];
#pragma unroll
            for (int n = 0; n < 4; ++n)
                kf[n] = *(const bf16x8*)(Kb +
                                         (rowbase + kv0 + n * 16 + r16) *
                                             D_MODEL +
                                         hcol + c * 32 + g * 8);
#pragma unroll
            for (int n = 0; n < 4; ++n)
#pragma unroll
                for (int m = 0; m < 2; ++m)
                    s[m][n] = __builtin_amdgcn_mfma_f32_16x16x32_bf16(
                        aq[m][c], kf[n], s[m][n], 0, 0, 0);
        }

        // ---- causal mask (diagonal tiles only) ----
        if (kv0 + 63 > qbase) {
#pragma unroll
            for (int m = 0; m < 2; ++m)
#pragma unroll
                for (int n = 0; n < 4; ++n)
#pragma unroll
                    for (int r = 0; r < 4; ++r) {
                        int kvg = kv0 + n * 16 + r16;
                        int qg  = qbase + m * 16 + g * 4 + r;
                        if (kvg > qg) s[m][n][r] = -3.0e38f;
                    }
        }

        // ---- online softmax ----
        float tm[2][4];
#pragma unroll
        for (int m = 0; m < 2; ++m)
#pragma unroll
            for (int r = 0; r < 4; ++r)
                tm[m][r] = fmaxf(fmaxf(s[m][0][r], s[m][1][r]),
                                 fmaxf(s[m][2][r], s[m][3][r]));
#pragma unroll
        for (int d = 1; d < 16; d <<= 1)
#pragma unroll
            for (int m = 0; m < 2; ++m)
#pragma unroll
                for (int r = 0; r < 4; ++r)
                    tm[m][r] = fmaxf(tm[m][r], __shfl_xor(tm[m][r], d));

        float alpha[2][4];
#pragma unroll
        for (int m = 0; m < 2; ++m)
#pragma unroll
            for (int r = 0; r < 4; ++r) {
                float nm    = fmaxf(m_run[m][r], tm[m][r]);
                alpha[m][r] = __expf(m_run[m][r] - nm);
                m_run[m][r] = nm;
            }
#pragma unroll
        for (int m = 0; m < 2; ++m)
#pragma unroll
            for (int n = 0; n < 4; ++n)
#pragma unroll
                for (int r = 0; r < 4; ++r)
                    s[m][n][r] = __expf(s[m][n][r] - m_run[m][r]);

        float rs[2][4];
#pragma unroll
        for (int m = 0; m < 2; ++m)
#pragma unroll
            for (int r = 0; r < 4; ++r)
                rs[m][r] = (s[m][0][r] + s[m][1][r]) + (s[m][2][r] + s[m][3][r]);
#pragma unroll
        for (int d = 1; d < 16; d <<= 1)
#pragma unroll
            for (int m = 0; m < 2; ++m)
#pragma unroll
                for (int r = 0; r < 4; ++r) rs[m][r] += __shfl_xor(rs[m][r], d);
#pragma unroll
        for (int m = 0; m < 2; ++m)
#pragma unroll
            for (int r = 0; r < 4; ++r)
                l_run[m][r] = l_run[m][r] * alpha[m][r] + rs[m][r];
#pragma unroll
        for (int m = 0; m < 2; ++m)
#pragma unroll
            for (int dt = 0; dt < 8; ++dt)
#pragma unroll
                for (int r = 0; r < 4; ++r) o[m][dt][r] *= alpha[m][r];

        // ---- P -> LDS (transpose to A-frag layout) ----
#pragma unroll
        for (int m = 0; m < 2; ++m)
#pragma unroll
            for (int n = 0; n < 4; ++n)
#pragma unroll
                for (int r = 0; r < 4; ++r)
                    P_lds[wid][m * 16 + g * 4 + r][n * 16 + r16] =
                        f2bf(s[m][n][r]);

        bf16x8 pa[2][2];
#pragma unroll
        for (int m = 0; m < 2; ++m)
#pragma unroll
            for (int c = 0; c < 2; ++c)
                pa[m][c] =
                    *(const bf16x8*)&P_lds[wid][m * 16 + r16][c * 32 + g * 8];

        // ---- PV ----
        const bf16* vp = Vt + ((size_t)bh * DK) * SEQ + kv0 + g * 8;
#pragma unroll
        for (int dt = 0; dt < 8; ++dt) {
            bf16x8 bv[2];
#pragma unroll
            for (int c = 0; c < 2; ++c)
                bv[c] = *(const bf16x8*)(vp + (size_t)(dt * 16 + r16) * SEQ +
                                         c * 32);
#pragma unroll
            for (int m = 0; m < 2; ++m)
#pragma unroll
                for (int c = 0; c < 2; ++c)
                    o[m][dt] = __builtin_amdgcn_mfma_f32_16x16x32_bf16(
                        pa[m][c], bv[c], o[m][dt], 0, 0, 0);
        }
    }

#pragma unroll
    for (int m = 0; m < 2; ++m) {
        float rl[4];
#pragma unroll
        for (int r = 0; r < 4; ++r) rl[r] = 1.f / l_run[m][r];
#pragma unroll
        for (int dt = 0; dt < 8; ++dt)
#pragma unroll
            for (int r = 0; r < 4; ++r) {
                float val = o[m][dt][r] * rl[r];
                AO[(rowbase + qbase + m * 16 + g * 4 + r) * D_MODEL + hcol +
                   dt * 16 + r16] = f2bf(val);
            }
    }
}

// ---------------- launch ----------------
extern "C" void kernel_launch(void* const* d_in, const int* in_sizes, int n_in,
                              void* d_out, int out_size, void* d_ws,
                              size_t ws_size, hipStream_t stream) {
    const float* X  = (const float*)d_in[0];
    const float* Wq = (const float*)d_in[1];
    const float* Wk = (const float*)d_in[2];
    const float* Wv = (const float*)d_in[3];
    const float* Wo = (const float*)d_in[4];

    bf16* base = (bf16*)d_ws;
    const size_t NX = (size_t)MROWS * D_MODEL;    // 8,388,608
    const size_t NW = (size_t)D_MODEL * D_MODEL;  // 4,194,304
    bf16* Xb  = base;
    bf16* Qb  = Xb + NX;
    bf16* Kbf = Qb + NX;
    bf16* Vt  = Kbf + NX;
    bf16* AOb = Vt + NX;
    bf16* Wqb = AOb + NX;   // Wq, Wk, Wv contiguous -> fused B [6144, 2048]
    bf16* Wkb = Wqb + NW;
    bf16* Wvb = Wkb + NW;
    bf16* Wob = Wvb + NW;
    (void)Wkb; (void)Wvb;

    cvt_all<<<2048, 256, 0, stream>>>(X, Wq, Wk, Wv, Wo, Xb, Wqb);

    // fused QKV projection: grid (6144/128, 4096/128) = (48, 32)
    gemm_qkv<<<dim3(48, 32), 256, 0, stream>>>(Xb, Wqb, Qb, Kbf, Vt);

    attn_fwd<<<dim3(16, 32), 256, 0, stream>>>(Qb, Kbf, Vt, AOb);

    gemm_o<<<dim3(16, 32), 256, 0, stream>>>(AOb, Wob, (float*)d_out);
}

// Round 8
// 457.633 us; speedup vs baseline: 1.1821x; 1.1821x over previous
//
#include <hip/hip_runtime.h>
#include <math.h>
#include <stdint.h>

#define D_MODEL 2048
#define NHEAD   16
#define DK      128
#define SEQ     2048
#define BATCH   2
#define MROWS   (BATCH * SEQ)   // 4096

typedef __bf16 bf16;
typedef __bf16 bf16x8 __attribute__((ext_vector_type(8)));
typedef __bf16 bf16x4 __attribute__((ext_vector_type(4)));
typedef float  f32x4  __attribute__((ext_vector_type(4)));

__device__ __forceinline__ bf16 f2bf(float f) {
    unsigned u = __builtin_bit_cast(unsigned, f);
    u += 0x7fffu + ((u >> 16) & 1u);   // round-to-nearest-even
    unsigned short h = (unsigned short)(u >> 16);
    return __builtin_bit_cast(bf16, h);
}

#define GLDS16(gp, lp)                                                        \
    __builtin_amdgcn_global_load_lds(                                         \
        (__attribute__((address_space(1))) void*)(uintptr_t)(gp),             \
        (__attribute__((address_space(3))) void*)(lp), 16, 0, 0)

#define QSCALE 0.08838834764831845f  // 1/sqrt(128)

// ---------------- fused fp32 -> bf16 convert (all 5 tensors, 1 launch) -----
__global__ void cvt_all(const float* __restrict__ X, const float* __restrict__ W0,
                        const float* __restrict__ W1, const float* __restrict__ W2,
                        const float* __restrict__ W3, bf16* __restrict__ dX,
                        bf16* __restrict__ dW) {
    const int NX4 = (MROWS * D_MODEL) / 4;            // 2,097,152
    const int NW4 = (D_MODEL * D_MODEL) / 4;          // 1,048,576 = 2^20
    const int TOT = NX4 + 4 * NW4;
    const int stride = gridDim.x * blockDim.x;
    for (int i = blockIdx.x * blockDim.x + threadIdx.x; i < TOT; i += stride) {
        const float* sp;
        bf16* dp;
        if (i < NX4) {
            sp = X + (size_t)i * 4;
            dp = dX + (size_t)i * 4;
        } else {
            int j = i - NX4;
            int s = j >> 20;
            int off = j & (NW4 - 1);
            const float* w = (s == 0) ? W0 : (s == 1) ? W1 : (s == 2) ? W2 : W3;
            sp = w + (size_t)off * 4;
            dp = dW + ((size_t)s << 22) + (size_t)off * 4;
        }
        float4 v = *(const float4*)sp;
        bf16x4 o;
        o[0] = f2bf(v.x); o[1] = f2bf(v.y); o[2] = f2bf(v.z); o[3] = f2bf(v.w);
        *(bf16x4*)dp = o;
    }
}

// ---------------- fused QKV GEMM ----------------
// C = X[4096,2048] @ Wqkv[6144,2048]^T.  Per-block epilogue:
//   cols [0,2048)    -> Qb  (bf16, scaled by QSCALE)
//   cols [2048,4096) -> Kbf (bf16)
//   cols [4096,6144) -> Vt  (bf16, transposed per (b,h): Vt[(b*16+h)*128+d][s])
__global__ __launch_bounds__(256)
void gemm_qkv(const bf16* __restrict__ A, const bf16* __restrict__ B,
              bf16* __restrict__ Qb, bf16* __restrict__ Kbf,
              bf16* __restrict__ Vt) {
    __shared__ alignas(16) bf16 sA[128 * 32];
    __shared__ alignas(16) bf16 sB[128 * 32];
    const int K = D_MODEL;

    const int tid  = threadIdx.x;
    const int lane = tid & 63;
    const int wid  = tid >> 6;
    const int wm   = wid >> 1, wn = wid & 1;
    const int brow = blockIdx.y * 128, bcol = blockIdx.x * 128;
    const int r16  = lane & 15, g = lane >> 4;

    f32x4 acc[4][4] = {};

    const int c0 = tid, c1 = 256 + tid;
    const int rowS0 = c0 >> 2, colS0 = (c0 & 3) * 8;
    const int rowS1 = c1 >> 2, colS1 = (c1 & 3) * 8;

    for (int kt = 0; kt < K; kt += 32) {
        GLDS16(A + (size_t)(brow + rowS0) * K + kt + colS0, &sA[c0 * 8]);
        GLDS16(A + (size_t)(brow + rowS1) * K + kt + colS1, &sA[c1 * 8]);
        GLDS16(B + (size_t)(bcol + rowS0) * K + kt + colS0, &sB[c0 * 8]);
        GLDS16(B + (size_t)(bcol + rowS1) * K + kt + colS1, &sB[c1 * 8]);
        __syncthreads();

        bf16x8 af[4], bfr[4];
#pragma unroll
        for (int m = 0; m < 4; ++m)
            af[m] = *(const bf16x8*)&sA[(wm * 64 + m * 16 + r16) * 32 + g * 8];
#pragma unroll
        for (int n = 0; n < 4; ++n)
            bfr[n] = *(const bf16x8*)&sB[(wn * 64 + n * 16 + r16) * 32 + g * 8];
#pragma unroll
        for (int m = 0; m < 4; ++m)
#pragma unroll
            for (int n = 0; n < 4; ++n)
                acc[m][n] = __builtin_amdgcn_mfma_f32_16x16x32_bf16(
                    af[m], bfr[n], acc[m][n], 0, 0, 0);
        __syncthreads();
    }

    const int which = bcol >> 11;  // 0=Q, 1=K, 2=V (tiles never straddle)
#pragma unroll
    for (int m = 0; m < 4; ++m) {
#pragma unroll
        for (int n = 0; n < 4; ++n) {
            const int col  = bcol + wn * 64 + n * 16 + r16;
            const int row0 = brow + wm * 64 + m * 16 + g * 4;
            if (which == 0) {
#pragma unroll
                for (int r = 0; r < 4; ++r)
                    Qb[(size_t)(row0 + r) * D_MODEL + col] =
                        f2bf(acc[m][n][r] * QSCALE);
            } else if (which == 1) {
#pragma unroll
                for (int r = 0; r < 4; ++r)
                    Kbf[(size_t)(row0 + r) * D_MODEL + (col - 2048)] =
                        f2bf(acc[m][n][r]);
            } else {
                const int b = row0 >> 11, s = row0 & 2047;
                bf16x4 v;
#pragma unroll
                for (int r = 0; r < 4; ++r) v[r] = f2bf(acc[m][n][r]);
                *(bf16x4*)&Vt[(size_t)(b * 2048 + (col - 4096)) * 2048 + s] = v;
            }
        }
    }
}

// ---------------- O-projection GEMM (bf16 in, fp32 out) ----------------
__global__ __launch_bounds__(256)
void gemm_o(const bf16* __restrict__ A, const bf16* __restrict__ B,
            float* __restrict__ C) {
    __shared__ alignas(16) bf16 sA[128 * 32];
    __shared__ alignas(16) bf16 sB[128 * 32];
    const int K = D_MODEL, N = D_MODEL;

    const int tid  = threadIdx.x;
    const int lane = tid & 63;
    const int wid  = tid >> 6;
    const int wm   = wid >> 1, wn = wid & 1;
    const int brow = blockIdx.y * 128, bcol = blockIdx.x * 128;
    const int r16  = lane & 15, g = lane >> 4;

    f32x4 acc[4][4] = {};

    const int c0 = tid, c1 = 256 + tid;
    const int rowS0 = c0 >> 2, colS0 = (c0 & 3) * 8;
    const int rowS1 = c1 >> 2, colS1 = (c1 & 3) * 8;

    for (int kt = 0; kt < K; kt += 32) {
        GLDS16(A + (size_t)(brow + rowS0) * K + kt + colS0, &sA[c0 * 8]);
        GLDS16(A + (size_t)(brow + rowS1) * K + kt + colS1, &sA[c1 * 8]);
        GLDS16(B + (size_t)(bcol + rowS0) * K + kt + colS0, &sB[c0 * 8]);
        GLDS16(B + (size_t)(bcol + rowS1) * K + kt + colS1, &sB[c1 * 8]);
        __syncthreads();

        bf16x8 af[4], bfr[4];
#pragma unroll
        for (int m = 0; m < 4; ++m)
            af[m] = *(const bf16x8*)&sA[(wm * 64 + m * 16 + r16) * 32 + g * 8];
#pragma unroll
        for (int n = 0; n < 4; ++n)
            bfr[n] = *(const bf16x8*)&sB[(wn * 64 + n * 16 + r16) * 32 + g * 8];
#pragma unroll
        for (int m = 0; m < 4; ++m)
#pragma unroll
            for (int n = 0; n < 4; ++n)
                acc[m][n] = __builtin_amdgcn_mfma_f32_16x16x32_bf16(
                    af[m], bfr[n], acc[m][n], 0, 0, 0);
        __syncthreads();
    }

#pragma unroll
    for (int m = 0; m < 4; ++m)
#pragma unroll
        for (int n = 0; n < 4; ++n) {
            const int col  = bcol + wn * 64 + n * 16 + r16;
            const int row0 = brow + wm * 64 + m * 16 + g * 4;
#pragma unroll
            for (int r = 0; r < 4; ++r)
                C[(size_t)(row0 + r) * N + col] = acc[m][n][r];
        }
}

// ---------------- causal flash attention ----------------
// 512 blocks, all co-resident (2/CU). Dispatch model: XCD = lin%8 round-robin,
// slot = (lin>>3)&31 = CU within XCD, r = lin>>8 = residency round (0/1).
//   bh = xcd*4 + (slot&3): all 16 q-tiles of a head on ONE XCD (4 heads/XCD,
//        K+V = 4 MB = one XCD L2)  -> low FETCH (verified 24.7 MB round 6)
//   qt = r ? 15-(slot>>2) : slot>>2: each CU's resident pair = (qt, 15-qt)
//        -> exactly 17 kv-tile-units per CU (fixes round-6 imbalance)
// 4 waves x 32 q-rows, KVBLK=64, no barriers; V loads issued before softmax.
__global__ __launch_bounds__(256, 2)
void attn_fwd(const bf16* __restrict__ Q, const bf16* __restrict__ Kb,
              const bf16* __restrict__ Vt, bf16* __restrict__ AO) {
    __shared__ alignas(16) bf16 P_lds[4][32][72];  // 144B row stride

    const int tid  = threadIdx.x;
    const int lane = tid & 63;
    const int wid  = tid >> 6;
    const int r16  = lane & 15, g = lane >> 4;
    const int lin  = (int)blockIdx.x + 16 * (int)blockIdx.y;
    const int xcd  = lin & 7;
    const int slot = (lin >> 3) & 31;
    const int rr   = lin >> 8;
    const int bh   = xcd * 4 + (slot & 3);
    const int qt   = rr ? (15 - (slot >> 2)) : (slot >> 2);
    const int b    = bh >> 4;
    const int qbase = qt * 128 + wid * 32;
    const size_t rowbase = (size_t)b * SEQ;
    const int hcol = (bh & 15) * DK;

    // Q fragments (pre-scaled by QSCALE in gemm_qkv epilogue)
    bf16x8 aq[2][4];
#pragma unroll
    for (int m = 0; m < 2; ++m) {
        const bf16* qp =
            Q + (rowbase + qbase + m * 16 + r16) * D_MODEL + hcol + g * 8;
#pragma unroll
        for (int c = 0; c < 4; ++c) aq[m][c] = *(const bf16x8*)(qp + c * 32);
    }

    f32x4 o[2][8] = {};
    float m_run[2][4], l_run[2][4];
#pragma unroll
    for (int m = 0; m < 2; ++m)
#pragma unroll
        for (int r = 0; r < 4; ++r) {
            m_run[m][r] = -3.0e38f;
            l_run[m][r] = 0.f;
        }

    const int ntile = (qbase >> 6) + 1;  // kv tiles of 64
    for (int t = 0; t < ntile; ++t) {
        const int kv0 = t * 64;

        // ---- QK^T (K direct from global; rows L2-resident per-XCD) ----
        f32x4 s[2][4] = {};
#pragma unroll
        for (int c = 0; c < 4; ++c) {
            bf16x8 kf[4];
#pragma unroll
            for (int n = 0; n < 4; ++n)
                kf[n] = *(const bf16x8*)(Kb +
                                         (rowbase + kv0 + n * 16 + r16) *
                                             D_MODEL +
                                         hcol + c * 32 + g * 8);
#pragma unroll
            for (int n = 0; n < 4; ++n)
#pragma unroll
                for (int m = 0; m < 2; ++m)
                    s[m][n] = __builtin_amdgcn_mfma_f32_16x16x32_bf16(
                        aq[m][c], kf[n], s[m][n], 0, 0, 0);
        }

        // ---- early V issue: latency hides under mask+softmax ----
        bf16x8 bv[8][2];
        const bf16* vp = Vt + ((size_t)bh * DK) * SEQ + kv0 + g * 8;
#pragma unroll
        for (int dt = 0; dt < 8; ++dt)
#pragma unroll
            for (int c = 0; c < 2; ++c)
                bv[dt][c] = *(const bf16x8*)(vp +
                                             (size_t)(dt * 16 + r16) * SEQ +
                                             c * 32);

        // ---- causal mask (diagonal tiles only) ----
        if (kv0 + 63 > qbase) {
#pragma unroll
            for (int m = 0; m < 2; ++m)
#pragma unroll
                for (int n = 0; n < 4; ++n)
#pragma unroll
                    for (int r = 0; r < 4; ++r) {
                        int kvg = kv0 + n * 16 + r16;
                        int qg  = qbase + m * 16 + g * 4 + r;
                        if (kvg > qg) s[m][n][r] = -3.0e38f;
                    }
        }

        // ---- online softmax ----
        float tm[2][4];
#pragma unroll
        for (int m = 0; m < 2; ++m)
#pragma unroll
            for (int r = 0; r < 4; ++r)
                tm[m][r] = fmaxf(fmaxf(s[m][0][r], s[m][1][r]),
                                 fmaxf(s[m][2][r], s[m][3][r]));
#pragma unroll
        for (int d = 1; d < 16; d <<= 1)
#pragma unroll
            for (int m = 0; m < 2; ++m)
#pragma unroll
                for (int r = 0; r < 4; ++r)
                    tm[m][r] = fmaxf(tm[m][r], __shfl_xor(tm[m][r], d));

        float alpha[2][4];
#pragma unroll
        for (int m = 0; m < 2; ++m)
#pragma unroll
            for (int r = 0; r < 4; ++r) {
                float nm    = fmaxf(m_run[m][r], tm[m][r]);
                alpha[m][r] = __expf(m_run[m][r] - nm);
                m_run[m][r] = nm;
            }
#pragma unroll
        for (int m = 0; m < 2; ++m)
#pragma unroll
            for (int n = 0; n < 4; ++n)
#pragma unroll
                for (int r = 0; r < 4; ++r)
                    s[m][n][r] = __expf(s[m][n][r] - m_run[m][r]);

        float rs[2][4];
#pragma unroll
        for (int m = 0; m < 2; ++m)
#pragma unroll
            for (int r = 0; r < 4; ++r)
                rs[m][r] = (s[m][0][r] + s[m][1][r]) + (s[m][2][r] + s[m][3][r]);
#pragma unroll
        for (int d = 1; d < 16; d <<= 1)
#pragma unroll
            for (int m = 0; m < 2; ++m)
#pragma unroll
                for (int r = 0; r < 4; ++r) rs[m][r] += __shfl_xor(rs[m][r], d);
#pragma unroll
        for (int m = 0; m < 2; ++m)
#pragma unroll
            for (int r = 0; r < 4; ++r)
                l_run[m][r] = l_run[m][r] * alpha[m][r] + rs[m][r];
#pragma unroll
        for (int m = 0; m < 2; ++m)
#pragma unroll
            for (int dt = 0; dt < 8; ++dt)
#pragma unroll
                for (int r = 0; r < 4; ++r) o[m][dt][r] *= alpha[m][r];

        // ---- P -> LDS (transpose to A-frag layout) ----
#pragma unroll
        for (int m = 0; m < 2; ++m)
#pragma unroll
            for (int n = 0; n < 4; ++n)
#pragma unroll
                for (int r = 0; r < 4; ++r)
                    P_lds[wid][m * 16 + g * 4 + r][n * 16 + r16] =
                        f2bf(s[m][n][r]);

        bf16x8 pa[2][2];
#pragma unroll
        for (int m = 0; m < 2; ++m)
#pragma unroll
            for (int c = 0; c < 2; ++c)
                pa[m][c] =
                    *(const bf16x8*)&P_lds[wid][m * 16 + r16][c * 32 + g * 8];

        // ---- PV (V already in registers) ----
#pragma unroll
        for (int dt = 0; dt < 8; ++dt)
#pragma unroll
            for (int m = 0; m < 2; ++m)
#pragma unroll
                for (int c = 0; c < 2; ++c)
                    o[m][dt] = __builtin_amdgcn_mfma_f32_16x16x32_bf16(
                        pa[m][c], bv[dt][c], o[m][dt], 0, 0, 0);
    }

#pragma unroll
    for (int m = 0; m < 2; ++m) {
        float rl[4];
#pragma unroll
        for (int r = 0; r < 4; ++r) rl[r] = 1.f / l_run[m][r];
#pragma unroll
        for (int dt = 0; dt < 8; ++dt)
#pragma unroll
            for (int r = 0; r < 4; ++r) {
                float val = o[m][dt][r] * rl[r];
                AO[(rowbase + qbase + m * 16 + g * 4 + r) * D_MODEL + hcol +
                   dt * 16 + r16] = f2bf(val);
            }
    }
}

// ---------------- launch ----------------
extern "C" void kernel_launch(void* const* d_in, const int* in_sizes, int n_in,
                              void* d_out, int out_size, void* d_ws,
                              size_t ws_size, hipStream_t stream) {
    const float* X  = (const float*)d_in[0];
    const float* Wq = (const float*)d_in[1];
    const float* Wk = (const float*)d_in[2];
    const float* Wv = (const float*)d_in[3];
    const float* Wo = (const float*)d_in[4];

    bf16* base = (bf16*)d_ws;
    const size_t NX = (size_t)MROWS * D_MODEL;    // 8,388,608
    const size_t NW = (size_t)D_MODEL * D_MODEL;  // 4,194,304
    bf16* Xb  = base;
    bf16* Qb  = Xb + NX;
    bf16* Kbf = Qb + NX;
    bf16* Vt  = Kbf + NX;
    bf16* AOb = Vt + NX;
    bf16* Wqb = AOb + NX;   // Wq, Wk, Wv contiguous -> fused B [6144, 2048]
    bf16* Wkb = Wqb + NW;
    bf16* Wvb = Wkb + NW;
    bf16* Wob = Wvb + NW;
    (void)Wkb; (void)Wvb;

    cvt_all<<<2048, 256, 0, stream>>>(X, Wq, Wk, Wv, Wo, Xb, Wqb);

    // fused QKV projection: grid (6144/128, 4096/128) = (48, 32)
    gemm_qkv<<<dim3(48, 32), 256, 0, stream>>>(Xb, Wqb, Qb, Kbf, Vt);

    attn_fwd<<<dim3(16, 32), 256, 0, stream>>>(Qb, Kbf, Vt, AOb);

    gemm_o<<<dim3(16, 32), 256, 0, stream>>>(AOb, Wob, (float*)d_out);
}